// Round 7
// baseline (5237.579 us; speedup 1.0000x reference)
//
#include <hip/hip_runtime.h>

typedef unsigned short u16;
typedef unsigned int u32;
typedef unsigned long long u64;
typedef __attribute__((ext_vector_type(8))) short short8;
typedef __attribute__((ext_vector_type(4))) float float4_t;
typedef __attribute__((ext_vector_type(2))) u32 u32x2;
typedef __attribute__((ext_vector_type(4))) u32 u32x4;

__device__ __forceinline__ u16 f2bf(float f) {
    union { float f; u32 u; } x; x.f = f;
    u32 r = x.u + 0x7FFFu + ((x.u >> 16) & 1u);
    return (u16)(r >> 16);
}
__device__ __forceinline__ float bitsf(u32 u) {
    union { u32 u; float f; } x; x.u = u; return x.f;
}
// pack two floats' (biased-rounded) bf16 into one u32: [hi:lo]
__device__ __forceinline__ u32 pk2bf(float hi, float lo) {
    union { float f; u32 u; } a, b; a.f = hi; b.f = lo;
    return __builtin_amdgcn_perm(a.u + 0x8000u, b.u + 0x8000u, 0x07060302u);
}
#define LOG2E 1.44269504088896340736f
__device__ __forceinline__ float tanh_(float x) {  // 1 - 2/(1+e^{2x})
    float t = __builtin_amdgcn_exp2f(2.f * LOG2E * x);
    return 1.f - 2.f * __builtin_amdgcn_rcpf(1.f + t);
}

__device__ __forceinline__ float4_t mfma16(short8 a, short8 b, float4_t c) {
    return __builtin_amdgcn_mfma_f32_16x16x32_bf16(a, b, c, 0, 0, 0);
}

// fragment loaders: 8 contiguous K-elements starting at p
__device__ __forceinline__ short8 ldfrag(const u16* p) { return *(const short8*)p; }
__device__ __forceinline__ short8 ldfrag(const float* p) {
    float4_t a = *(const float4_t*)p;
    float4_t b = *(const float4_t*)(p + 4);
    short8 r;
#pragma unroll
    for (int j = 0; j < 4; ++j) { r[j] = (short)f2bf(a[j]); r[4 + j] = (short)f2bf(b[j]); }
    return r;
}

// ---------------------------------------------------------------------------
// gemm_ih: Xih[M,512](bf16) = scale(col) * (A[M,128] @ W[512,128]^T + b1 + b2)
// Gate pre-activations pre-scaled: i,f,o cols get -log2e; g cols +2log2e.
// Block (0,0) also zeroes stats[0..256).
// ---------------------------------------------------------------------------
template<typename AT>
__global__ __launch_bounds__(256) void gemm_ih(
    const AT* __restrict__ A, const float* __restrict__ W,
    const float* __restrict__ b1, const float* __restrict__ b2,
    u16* __restrict__ C, float* __restrict__ stats, int M)
{
    if (blockIdx.x == 0 && blockIdx.y == 0) stats[threadIdx.x] = 0.f;
    const int P = 512;
    const int lane = threadIdx.x & 63;
    const int w    = threadIdx.x >> 6;
    const int l15  = lane & 15;
    const int quad = lane >> 4;
    const int rowbase = blockIdx.x * 64;
    const int colbase = blockIdx.y * 128 + w * 32;

    short8 af[4][4];
#pragma unroll
    for (int mb = 0; mb < 4; ++mb) {
        int row = rowbase + mb * 16 + l15;
        if (row >= M) row = M - 1;
        const AT* ap = A + (size_t)row * 128 + quad * 8;
#pragma unroll
        for (int kb = 0; kb < 4; ++kb) af[mb][kb] = ldfrag(ap + kb * 32);
    }
    short8 bfr[2][4];
#pragma unroll
    for (int nb = 0; nb < 2; ++nb) {
        int col = colbase + nb * 16 + l15;
        const float* wp = W + (size_t)col * 128 + quad * 8;
#pragma unroll
        for (int kb = 0; kb < 4; ++kb) bfr[nb][kb] = ldfrag(wp + kb * 32);
    }
    const float4_t z4 = {0.f, 0.f, 0.f, 0.f};
    float bias[2], scl[2];
#pragma unroll
    for (int nb = 0; nb < 2; ++nb) {
        int col = colbase + nb * 16 + l15;
        bias[nb] = b1[col] + b2[col];
        scl[nb] = (col >= 256 && col < 384) ? (2.f * LOG2E) : (-LOG2E);
    }
#pragma unroll
    for (int mb = 0; mb < 4; ++mb)
#pragma unroll
        for (int nb = 0; nb < 2; ++nb) {
            float4_t a = z4;
#pragma unroll
            for (int kb = 0; kb < 4; ++kb) a = mfma16(af[mb][kb], bfr[nb][kb], a);
#pragma unroll
            for (int r = 0; r < 4; ++r) {
                int row = rowbase + mb * 16 + quad * 4 + r;
                int col = colbase + nb * 16 + l15;
                if (row < M) C[(size_t)row * P + col] = f2bf((a[r] + bias[nb]) * scl[nb]);
            }
        }
}

// ---------------------------------------------------------------------------
// gemm_out: P[M,128](f32) = A1@W1^T + A2@W2^T + bias ; per-col sum/sumsq atomics
// ---------------------------------------------------------------------------
template<typename T>
__device__ __forceinline__ void accum_gemm(
    const T* __restrict__ A, const float* __restrict__ W,
    float4_t (&acc)[4][2], int M, int rowbase, int colbase, int l15, int quad)
{
    short8 af[4][4];
#pragma unroll
    for (int mb = 0; mb < 4; ++mb) {
        int row = rowbase + mb * 16 + l15;
        if (row >= M) row = M - 1;
        const T* ap = A + (size_t)row * 128 + quad * 8;
#pragma unroll
        for (int kb = 0; kb < 4; ++kb) af[mb][kb] = ldfrag(ap + kb * 32);
    }
    short8 bfr[2][4];
#pragma unroll
    for (int nb = 0; nb < 2; ++nb) {
        int col = colbase + nb * 16 + l15;
        const float* wp = W + (size_t)col * 128 + quad * 8;
#pragma unroll
        for (int kb = 0; kb < 4; ++kb) bfr[nb][kb] = ldfrag(wp + kb * 32);
    }
#pragma unroll
    for (int mb = 0; mb < 4; ++mb)
#pragma unroll
        for (int nb = 0; nb < 2; ++nb)
#pragma unroll
            for (int kb = 0; kb < 4; ++kb)
                acc[mb][nb] = mfma16(af[mb][kb], bfr[nb][kb], acc[mb][nb]);
}

template<typename AT2>
__global__ __launch_bounds__(256) void gemm_out(
    const u16* __restrict__ A1, const float* __restrict__ W1,
    const AT2* __restrict__ A2, const float* __restrict__ W2,
    const float* __restrict__ bias, float* __restrict__ C,
    float* __restrict__ stats, int M)
{
    const int P = 128;
    const int lane = threadIdx.x & 63;
    const int w    = threadIdx.x >> 6;
    const int l15  = lane & 15;
    const int quad = lane >> 4;
    const int rowbase = blockIdx.x * 64;
    const int colbase = w * 32;

    float4_t acc[4][2];
    const float4_t z4 = {0.f, 0.f, 0.f, 0.f};
#pragma unroll
    for (int mb = 0; mb < 4; ++mb)
#pragma unroll
        for (int nb = 0; nb < 2; ++nb) acc[mb][nb] = z4;

    accum_gemm(A1, W1, acc, M, rowbase, colbase, l15, quad);
    accum_gemm(A2, W2, acc, M, rowbase, colbase, l15, quad);

    float s[2] = {0.f, 0.f}, sq[2] = {0.f, 0.f};
#pragma unroll
    for (int nb = 0; nb < 2; ++nb) {
        int col = colbase + nb * 16 + l15;
        float bb = bias[col];
#pragma unroll
        for (int mb = 0; mb < 4; ++mb)
#pragma unroll
            for (int r = 0; r < 4; ++r) {
                int row = rowbase + mb * 16 + quad * 4 + r;
                if (row < M) {
                    float v = acc[mb][nb][r] + bb;
                    C[(size_t)row * P + col] = v;
                    s[nb] += v; sq[nb] += v * v;
                }
            }
    }
#pragma unroll
    for (int nb = 0; nb < 2; ++nb) {
        float t1 = s[nb], t2 = sq[nb];
        t1 += __shfl_xor(t1, 16); t1 += __shfl_xor(t1, 32);
        t2 += __shfl_xor(t2, 16); t2 += __shfl_xor(t2, 32);
        int col = colbase + nb * 16 + l15;
        if (quad == 0) atomicAdd(&stats[col], t1);
        if (quad == 1) atomicAdd(&stats[P + col], t2);
    }
}

// ---------------------------------------------------------------------------
// Barrier-free LSTM aggregator, wave-owns-nodes decomposition.
// 512 thr (8 waves), 256 nodes/block, wave w owns nodes base+32w .. +31
// (two 16-node MFMA n-tiles). Whh staged ONCE in LDS (bf16, gate-pre-scaled,
// chunk c of row R stored at slot c^(R&15): A-frag ds_read_b128 at the
// uniform 8-access/bank floor instead of 16-way conflict). h(t) lives in
// registers as B-frags; the quad-lane dim redistribution goes through a
// 2 KB wave-PRIVATE LDS scratch (in-order ds ops, no barrier). The only
// __syncthreads is after Whh staging — the 16-step recurrence has zero
// convergence points.
// __launch_bounds__(512, 1): LDS (147 KB) caps residency at 1 block/CU
// anyway (2 waves/SIMD), and at that occupancy the HW VGPR budget is
// 256/wave. Round 6 omitted the min-blocks arg -> compiler assumed a
// 128-VGPR budget against ~240 demand -> 768 MB/dispatch spill traffic
// (WRITE_SIZE canary). The 2nd arg = min BLOCKS/CU on this HIP (rounds 1/5).
// ---------------------------------------------------------------------------
__global__ __launch_bounds__(512, 1) void lstm_kernel(
    const u16* __restrict__ Xih,   // [N,512] bf16, pre-scaled gate order i,f,g,o
    const int* __restrict__ nbr,   // [N,16]
    const float* __restrict__ Whh, // [512,128] f32 (scaled at staging)
    u16* __restrict__ Hout,        // [N,128] bf16
    int N)
{
    __shared__ u16 whs[512 * 128];     // 128 KB swizzled Whh (bf16)
    __shared__ u32 scr[8][32][16];     // 16 KB: per-wave h-redistribution scratch
    const int tid  = threadIdx.x;
    const int lane = tid & 63;
    const int w    = tid >> 6;           // wave 0..7
    const int l15  = lane & 15;
    const int quad = lane >> 4;
    const int base = blockIdx.x * 256;

    // ---- stage Whh -> LDS: bf16, gate-scaled, chunk-swizzled (coalesced) ----
    for (int i = tid; i < 512 * 16; i += 512) {
        const int R = i >> 4, cch = i & 15;
        const float s = ((R >> 7) == 2) ? (2.f * LOG2E) : (-LOG2E);
        const float* wp = Whh + (size_t)R * 128 + cch * 8;
        float4_t a = *(const float4_t*)wp;
        float4_t b = *(const float4_t*)(wp + 4);
        u32x4 pk;
        pk[0] = ((u32)f2bf(a[1] * s) << 16) | f2bf(a[0] * s);
        pk[1] = ((u32)f2bf(a[3] * s) << 16) | f2bf(a[2] * s);
        pk[2] = ((u32)f2bf(b[1] * s) << 16) | f2bf(b[0] * s);
        pk[3] = ((u32)f2bf(b[3] * s) << 16) | f2bf(b[2] * s);
        *(u32x4*)&whs[R * 128 + ((cch ^ (R & 15)) << 3)] = pk;
    }
    __syncthreads();

    // owners (clamped for tail block)
    const int own0s = base + w * 32 + l15;
    const int own1s = own0s + 16;
    const int own0 = own0s < N ? own0s : N - 1;
    const int own1 = own1s < N ? own1s : N - 1;

    int xcur0 = nbr[(size_t)own0 * 16];
    int xcur1 = nbr[(size_t)own1 * 16];

    const float4_t z4 = {0.f, 0.f, 0.f, 0.f};
    float4_t c[8][2];
#pragma unroll
    for (int dc = 0; dc < 8; ++dc) { c[dc][0] = z4; c[dc][1] = z4; }
    const short8 zs8 = {0, 0, 0, 0, 0, 0, 0, 0};
    short8 hfA[2][4];
#pragma unroll
    for (int n = 0; n < 2; ++n)
#pragma unroll
        for (int kb = 0; kb < 4; ++kb) hfA[n][kb] = zs8;

    for (int t = 0; t < 16; ++t) {
        int xn0 = 0, xn1 = 0;
        if (t < 15) {   // prefetch next step's neighbor ids (L2-resident table)
            xn0 = nbr[(size_t)own0 * 16 + t + 1];
            xn1 = nbr[(size_t)own1 * 16 + t + 1];
        }
        const u16* bp0 = Xih + (size_t)xcur0 * 512 + 4 * quad;
        const u16* bp1 = Xih + (size_t)xcur1 * 512 + 4 * quad;

        u32x2 gb[2][2][4];   // [parity][n][gate] gather pipeline, 1 dc ahead
#pragma unroll
        for (int g = 0; g < 4; ++g) {
            gb[0][0][g] = *(const u32x2*)(bp0 + 128 * g);
            gb[0][1][g] = *(const u32x2*)(bp1 + 128 * g);
        }
        short8 hfB[2][4];
#pragma unroll
        for (int dc = 0; dc < 8; ++dc) {
            const int par = dc & 1;
            if (dc < 7) {
#pragma unroll
                for (int g = 0; g < 4; ++g) {
                    gb[par ^ 1][0][g] = *(const u32x2*)(bp0 + 128 * g + 16 * (dc + 1));
                    gb[par ^ 1][1][g] = *(const u32x2*)(bp1 + 128 * g + 16 * (dc + 1));
                }
            }
            // z init from gathered Xih (accumulator layout)
            float4_t z[4][2];
#pragma unroll
            for (int g = 0; g < 4; ++g)
#pragma unroll
                for (int n = 0; n < 2; ++n) {
                    u32 w0 = gb[par][n][g][0], w1 = gb[par][n][g][1];
                    z[g][n][0] = bitsf(w0 << 16); z[g][n][1] = bitsf(w0 & 0xFFFF0000u);
                    z[g][n][2] = bitsf(w1 << 16); z[g][n][3] = bitsf(w1 & 0xFFFF0000u);
                }
            // recurrent GEMM: A-frag loaded once per (kb,g), reused for both n
#pragma unroll
            for (int kb = 0; kb < 4; ++kb)
#pragma unroll
                for (int g = 0; g < 4; ++g) {
                    const short8 whf = *(const short8*)&whs[
                        (128 * g + 16 * dc + l15) * 128 +
                        ((((kb << 2) | quad) ^ l15) << 3)];
                    z[g][0] = mfma16(whf, hfA[0][kb], z[g][0]);
                    z[g][1] = mfma16(whf, hfA[1][kb], z[g][1]);
                }
            // gates (pre-scaled domain), c update, h pack
#pragma unroll
            for (int n = 0; n < 2; ++n) {
                float4_t hv;
#pragma unroll
                for (int r = 0; r < 4; ++r) {
                    float i_ = __builtin_amdgcn_rcpf(1.f + __builtin_amdgcn_exp2f(z[0][n][r]));
                    float f_ = __builtin_amdgcn_rcpf(1.f + __builtin_amdgcn_exp2f(z[1][n][r]));
                    float g_ = 1.f - 2.f * __builtin_amdgcn_rcpf(1.f + __builtin_amdgcn_exp2f(z[2][n][r]));
                    float o_ = __builtin_amdgcn_rcpf(1.f + __builtin_amdgcn_exp2f(z[3][n][r]));
                    float cc = f_ * c[dc][n][r] + i_ * g_;
                    c[dc][n][r] = cc;
                    hv[r] = o_ * tanh_(cc);
                }
                u32x2 pr;
                pr[0] = pk2bf(hv[1], hv[0]);
                pr[1] = pk2bf(hv[3], hv[2]);
                if (t < 15) {
                    // wave-private scratch, B-frag slot for dims kl=16*par+4q+{0..3}
                    *(u32x2*)&scr[w][n * 16 + l15][8 * par + 2 * quad] = pr;
                } else {
                    const int own = n ? own1s : own0s;
                    if (own < N)
                        *(u32x2*)(Hout + (size_t)own * 128 + 16 * dc + 4 * quad) = pr;
                }
            }
            // after each dc pair, read back the completed kb-frag (in-order ds)
            if (par && t < 15) {
                const int kb = dc >> 1;
                hfB[0][kb] = *(const short8*)&scr[w][l15][4 * quad];
                hfB[1][kb] = *(const short8*)&scr[w][16 + l15][4 * quad];
            }
        }
        if (t < 15) {
#pragma unroll
            for (int n = 0; n < 2; ++n)
#pragma unroll
                for (int kb = 0; kb < 4; ++kb) hfA[n][kb] = hfB[n][kb];
            xcur0 = xn0; xcur1 = xn1;
        }
    }
}

// ---------------------------------------------------------------------------
__global__ void bn_prep(float* stats, const float* __restrict__ gamma,
                        const float* __restrict__ beta, float invN)
{
    int cidx = threadIdx.x;   // 0..127
    float s = stats[cidx], sq = stats[128 + cidx];
    float mu = s * invN;
    float var = sq * invN - mu * mu;
    float sc = gamma[cidx] * rsqrtf(var + 1e-5f);
    stats[256 + cidx] = sc;
    stats[384 + cidx] = beta[cidx] - mu * sc;
}

template<typename OT>
__global__ __launch_bounds__(256) void bn_apply(
    const float* __restrict__ X, const float* __restrict__ stats,
    OT* __restrict__ Y, int M, int relu)
{
    int gid = blockIdx.x * 256 + threadIdx.x;
    int row = gid >> 4;
    int cs  = (gid & 15) * 8;
    if (row >= M) return;
    float4_t a = *(const float4_t*)(X + (size_t)row * 128 + cs);
    float4_t b = *(const float4_t*)(X + (size_t)row * 128 + cs + 4);
    float v[8];
#pragma unroll
    for (int j = 0; j < 8; ++j) {
        float x = (j < 4) ? a[j] : b[j - 4];
        float t = x * stats[256 + cs + j] + stats[384 + cs + j];
        v[j] = relu ? fmaxf(t, 0.f) : t;
    }
    if constexpr (sizeof(OT) == 2) {
        short8 ov;
#pragma unroll
        for (int j = 0; j < 8; ++j) ov[j] = (short)f2bf(v[j]);
        *(short8*)((u16*)Y + (size_t)row * 128 + cs) = ov;
    } else {
        float4_t o1, o2;
#pragma unroll
        for (int j = 0; j < 4; ++j) { o1[j] = v[j]; o2[j] = v[4 + j]; }
        *(float4_t*)((float*)Y + (size_t)row * 128 + cs) = o1;
        *(float4_t*)((float*)Y + (size_t)row * 128 + cs + 4) = o2;
    }
}

// ---------------------------------------------------------------------------
extern "C" void kernel_launch(void* const* d_in, const int* in_sizes, int n_in,
                              void* d_out, int out_size, void* d_ws, size_t ws_size,
                              hipStream_t stream)
{
    const float* in_feat = (const float*)d_in[0];
    const int*   nbr     = (const int*)d_in[1];
    const float* Wih1 = (const float*)d_in[2];
    const float* Whh1 = (const float*)d_in[3];
    const float* bih1 = (const float*)d_in[4];
    const float* bhh1 = (const float*)d_in[5];
    const float* Wself1  = (const float*)d_in[6];
    const float* bself1  = (const float*)d_in[7];
    const float* Wneigh1 = (const float*)d_in[8];
    const float* gamma1  = (const float*)d_in[9];
    const float* beta1   = (const float*)d_in[10];
    const float* Wih2 = (const float*)d_in[11];
    const float* Whh2 = (const float*)d_in[12];
    const float* bih2 = (const float*)d_in[13];
    const float* bhh2 = (const float*)d_in[14];
    const float* Wself2  = (const float*)d_in[15];
    const float* bself2  = (const float*)d_in[16];
    const float* Wneigh2 = (const float*)d_in[17];
    const float* gamma2  = (const float*)d_in[18];
    const float* beta2   = (const float*)d_in[19];

    const int N = in_sizes[0] / 128;

    char* ws = (char*)d_ws;
    u16*   Xih   = (u16*)ws;                       // [N,512] bf16 (aliases Pbuf)
    float* Pbuf  = (float*)ws;                     // [N,128] f32
    u16*   hn    = (u16*)(ws + (size_t)N * 1024);  // [N,128] bf16
    float* stats = (float*)(ws + (size_t)N * 1024 + (size_t)N * 256);
    u16*   hcur  = (u16*)d_out;                    // bf16 scratch inside d_out

    const int nblk = (N + 63) / 64;
    const int lblk = (N + 255) / 256;
    const float invN = 1.0f / (float)N;
    const int bnblk = (N * 16 + 255) / 256;

    // ---------------- layer 1 ----------------
    gemm_ih<float><<<dim3(nblk, 4), dim3(256), 0, stream>>>(in_feat, Wih1, bih1, bhh1, Xih, stats, N);
    lstm_kernel<<<dim3(lblk), dim3(512), 0, stream>>>(Xih, nbr, Whh1, hn, N);
    gemm_out<float><<<dim3(nblk, 1), dim3(256), 0, stream>>>(hn, Wneigh1, in_feat, Wself1,
                                                             bself1, Pbuf, stats, N);
    bn_prep<<<dim3(1), dim3(128), 0, stream>>>(stats, gamma1, beta1, invN);
    bn_apply<u16><<<dim3(bnblk), dim3(256), 0, stream>>>(Pbuf, stats, hcur, N, 1);

    // ---------------- layer 2 ----------------
    gemm_ih<u16><<<dim3(nblk, 4), dim3(256), 0, stream>>>(hcur, Wih2, bih2, bhh2, Xih, stats, N);
    lstm_kernel<<<dim3(lblk), dim3(512), 0, stream>>>(Xih, nbr, Whh2, hn, N);
    gemm_out<u16><<<dim3(nblk, 1), dim3(256), 0, stream>>>(hn, Wneigh2, hcur, Wself2,
                                                           bself2, Pbuf, stats, N);
    bn_prep<<<dim3(1), dim3(128), 0, stream>>>(stats, gamma2, beta2, invN);
    bn_apply<float><<<dim3(bnblk), dim3(256), 0, stream>>>(Pbuf, stats, (float*)d_out, N, 0);
}

// Round 9
// 1592.087 us; speedup vs baseline: 3.2898x; 3.2898x over previous
//
#include <hip/hip_runtime.h>

typedef unsigned short u16;
typedef unsigned int u32;
typedef unsigned long long u64;
typedef __attribute__((ext_vector_type(8))) short short8;
typedef __attribute__((ext_vector_type(4))) float float4_t;
typedef __attribute__((ext_vector_type(2))) u32 u32x2;
typedef __attribute__((ext_vector_type(4))) u32 u32x4;

__device__ __forceinline__ u16 f2bf(float f) {
    union { float f; u32 u; } x; x.f = f;
    u32 r = x.u + 0x7FFFu + ((x.u >> 16) & 1u);
    return (u16)(r >> 16);
}
__device__ __forceinline__ float bitsf(u32 u) {
    union { u32 u; float f; } x; x.u = u; return x.f;
}
// pack two floats' (biased-rounded) bf16 into one u32: [hi:lo]
__device__ __forceinline__ u32 pk2bf(float hi, float lo) {
    union { float f; u32 u; } a, b; a.f = hi; b.f = lo;
    return __builtin_amdgcn_perm(a.u + 0x8000u, b.u + 0x8000u, 0x07060302u);
}
#define LOG2E 1.44269504088896340736f
__device__ __forceinline__ float tanh_(float x) {  // 1 - 2/(1+e^{2x})
    float t = __builtin_amdgcn_exp2f(2.f * LOG2E * x);
    return 1.f - 2.f * __builtin_amdgcn_rcpf(1.f + t);
}

__device__ __forceinline__ float4_t mfma16(short8 a, short8 b, float4_t c) {
    return __builtin_amdgcn_mfma_f32_16x16x32_bf16(a, b, c, 0, 0, 0);
}

// fragment loaders: 8 contiguous K-elements starting at p
__device__ __forceinline__ short8 ldfrag(const u16* p) { return *(const short8*)p; }
__device__ __forceinline__ short8 ldfrag(const float* p) {
    float4_t a = *(const float4_t*)p;
    float4_t b = *(const float4_t*)(p + 4);
    short8 r;
#pragma unroll
    for (int j = 0; j < 4; ++j) { r[j] = (short)f2bf(a[j]); r[4 + j] = (short)f2bf(b[j]); }
    return r;
}

// ---------------------------------------------------------------------------
// gemm_ih: Xih[M,512](bf16) = scale(col) * (A[M,128] @ W[512,128]^T + b1 + b2)
// Gate pre-activations pre-scaled: i,f,o cols get -log2e; g cols +2log2e.
// Block (0,0) also zeroes stats[0..256).
// ---------------------------------------------------------------------------
template<typename AT>
__global__ __launch_bounds__(256) void gemm_ih(
    const AT* __restrict__ A, const float* __restrict__ W,
    const float* __restrict__ b1, const float* __restrict__ b2,
    u16* __restrict__ C, float* __restrict__ stats, int M)
{
    if (blockIdx.x == 0 && blockIdx.y == 0) stats[threadIdx.x] = 0.f;
    const int P = 512;
    const int lane = threadIdx.x & 63;
    const int w    = threadIdx.x >> 6;
    const int l15  = lane & 15;
    const int quad = lane >> 4;
    const int rowbase = blockIdx.x * 64;
    const int colbase = blockIdx.y * 128 + w * 32;

    short8 af[4][4];
#pragma unroll
    for (int mb = 0; mb < 4; ++mb) {
        int row = rowbase + mb * 16 + l15;
        if (row >= M) row = M - 1;
        const AT* ap = A + (size_t)row * 128 + quad * 8;
#pragma unroll
        for (int kb = 0; kb < 4; ++kb) af[mb][kb] = ldfrag(ap + kb * 32);
    }
    short8 bfr[2][4];
#pragma unroll
    for (int nb = 0; nb < 2; ++nb) {
        int col = colbase + nb * 16 + l15;
        const float* wp = W + (size_t)col * 128 + quad * 8;
#pragma unroll
        for (int kb = 0; kb < 4; ++kb) bfr[nb][kb] = ldfrag(wp + kb * 32);
    }
    const float4_t z4 = {0.f, 0.f, 0.f, 0.f};
    float bias[2], scl[2];
#pragma unroll
    for (int nb = 0; nb < 2; ++nb) {
        int col = colbase + nb * 16 + l15;
        bias[nb] = b1[col] + b2[col];
        scl[nb] = (col >= 256 && col < 384) ? (2.f * LOG2E) : (-LOG2E);
    }
#pragma unroll
    for (int mb = 0; mb < 4; ++mb)
#pragma unroll
        for (int nb = 0; nb < 2; ++nb) {
            float4_t a = z4;
#pragma unroll
            for (int kb = 0; kb < 4; ++kb) a = mfma16(af[mb][kb], bfr[nb][kb], a);
#pragma unroll
            for (int r = 0; r < 4; ++r) {
                int row = rowbase + mb * 16 + quad * 4 + r;
                int col = colbase + nb * 16 + l15;
                if (row < M) C[(size_t)row * P + col] = f2bf((a[r] + bias[nb]) * scl[nb]);
            }
        }
}

// ---------------------------------------------------------------------------
// gemm_out: P[M,128](f32) = A1@W1^T + A2@W2^T + bias ; per-col sum/sumsq atomics
// ---------------------------------------------------------------------------
template<typename T>
__device__ __forceinline__ void accum_gemm(
    const T* __restrict__ A, const float* __restrict__ W,
    float4_t (&acc)[4][2], int M, int rowbase, int colbase, int l15, int quad)
{
    short8 af[4][4];
#pragma unroll
    for (int mb = 0; mb < 4; ++mb) {
        int row = rowbase + mb * 16 + l15;
        if (row >= M) row = M - 1;
        const T* ap = A + (size_t)row * 128 + quad * 8;
#pragma unroll
        for (int kb = 0; kb < 4; ++kb) af[mb][kb] = ldfrag(ap + kb * 32);
    }
    short8 bfr[2][4];
#pragma unroll
    for (int nb = 0; nb < 2; ++nb) {
        int col = colbase + nb * 16 + l15;
        const float* wp = W + (size_t)col * 128 + quad * 8;
#pragma unroll
        for (int kb = 0; kb < 4; ++kb) bfr[nb][kb] = ldfrag(wp + kb * 32);
    }
#pragma unroll
    for (int mb = 0; mb < 4; ++mb)
#pragma unroll
        for (int nb = 0; nb < 2; ++nb)
#pragma unroll
            for (int kb = 0; kb < 4; ++kb)
                acc[mb][nb] = mfma16(af[mb][kb], bfr[nb][kb], acc[mb][nb]);
}

template<typename AT2>
__global__ __launch_bounds__(256) void gemm_out(
    const u16* __restrict__ A1, const float* __restrict__ W1,
    const AT2* __restrict__ A2, const float* __restrict__ W2,
    const float* __restrict__ bias, float* __restrict__ C,
    float* __restrict__ stats, int M)
{
    const int P = 128;
    const int lane = threadIdx.x & 63;
    const int w    = threadIdx.x >> 6;
    const int l15  = lane & 15;
    const int quad = lane >> 4;
    const int rowbase = blockIdx.x * 64;
    const int colbase = w * 32;

    float4_t acc[4][2];
    const float4_t z4 = {0.f, 0.f, 0.f, 0.f};
#pragma unroll
    for (int mb = 0; mb < 4; ++mb)
#pragma unroll
        for (int nb = 0; nb < 2; ++nb) acc[mb][nb] = z4;

    accum_gemm(A1, W1, acc, M, rowbase, colbase, l15, quad);
    accum_gemm(A2, W2, acc, M, rowbase, colbase, l15, quad);

    float s[2] = {0.f, 0.f}, sq[2] = {0.f, 0.f};
#pragma unroll
    for (int nb = 0; nb < 2; ++nb) {
        int col = colbase + nb * 16 + l15;
        float bb = bias[col];
#pragma unroll
        for (int mb = 0; mb < 4; ++mb)
#pragma unroll
            for (int r = 0; r < 4; ++r) {
                int row = rowbase + mb * 16 + quad * 4 + r;
                if (row < M) {
                    float v = acc[mb][nb][r] + bb;
                    C[(size_t)row * P + col] = v;
                    s[nb] += v; sq[nb] += v * v;
                }
            }
    }
#pragma unroll
    for (int nb = 0; nb < 2; ++nb) {
        float t1 = s[nb], t2 = sq[nb];
        t1 += __shfl_xor(t1, 16); t1 += __shfl_xor(t1, 32);
        t2 += __shfl_xor(t2, 16); t2 += __shfl_xor(t2, 32);
        int col = colbase + nb * 16 + l15;
        if (quad == 0) atomicAdd(&stats[col], t1);
        if (quad == 1) atomicAdd(&stats[P + col], t2);
    }
}

// ---------------------------------------------------------------------------
// Barrier-free LSTM aggregator, wave-owns-nodes, 16 NODES/WAVE.
// 512 thr (8 waves), 128 nodes/block, wave w owns nodes base+16w..+15 (one
// MFMA n-tile). Whh staged once in LDS (bf16, gate-pre-scaled, chunk c of
// row R at slot c^(R&15) -> A-frag b128 reads at the uniform 8-access/bank
// floor). h(t) in registers as B-frags; quad-lane dim redistribution via a
// 1 KB wave-PRIVATE scr (in-order DS, no barrier). One __syncthreads total.
// Rounds 6/7: VGPR_Count pinned at 128 + 768 MB/dispatch spill. Law from
// (512,arg) data: budget = 512/(2*arg) for arg>=2, but arg=1 does NOT yield
// 256 — the backend has a default 4-waves/EU floor (=128 cap) that
// launch_bounds can't relax. amdgpu_waves_per_eu(2,2) overrides it: 2
// waves/EU is the TRUE occupancy here anyway (147 KB LDS -> 1 block/CU),
// so the 256-VGPR budget is free. Plus: 16 nodes/wave (~120 live regs) and
// sched_barrier(0) per dc-iteration to stop cross-iteration load hoisting.
// WRITE_SIZE is the spill canary (~25 MB = clean).
// ---------------------------------------------------------------------------
__global__ __launch_bounds__(512, 1) __attribute__((amdgpu_waves_per_eu(2, 2)))
void lstm_kernel(
    const u16* __restrict__ Xih,   // [N,512] bf16, pre-scaled gate order i,f,g,o
    const int* __restrict__ nbr,   // [N,16]
    const float* __restrict__ Whh, // [512,128] f32 (scaled at staging)
    u16* __restrict__ Hout,        // [N,128] bf16
    int N)
{
    __shared__ u16 whs[512 * 128];     // 128 KB swizzled Whh (bf16)
    __shared__ u32 scr[8][16][16];     // 8 KB: per-wave h-redistribution scratch
    const int tid  = threadIdx.x;
    const int lane = tid & 63;
    const int w    = tid >> 6;           // wave 0..7
    const int l15  = lane & 15;
    const int quad = lane >> 4;
    const int base = blockIdx.x * 128;

    // ---- stage Whh -> LDS: bf16, gate-scaled, chunk-swizzled (coalesced) ----
    for (int i = tid; i < 512 * 16; i += 512) {
        const int R = i >> 4, cch = i & 15;
        const float s = ((R >> 7) == 2) ? (2.f * LOG2E) : (-LOG2E);
        const float* wp = Whh + (size_t)R * 128 + cch * 8;
        float4_t a = *(const float4_t*)wp;
        float4_t b = *(const float4_t*)(wp + 4);
        u32x4 pk;
        pk[0] = ((u32)f2bf(a[1] * s) << 16) | f2bf(a[0] * s);
        pk[1] = ((u32)f2bf(a[3] * s) << 16) | f2bf(a[2] * s);
        pk[2] = ((u32)f2bf(b[1] * s) << 16) | f2bf(b[0] * s);
        pk[3] = ((u32)f2bf(b[3] * s) << 16) | f2bf(b[2] * s);
        *(u32x4*)&whs[R * 128 + ((cch ^ (R & 15)) << 3)] = pk;
    }
    __syncthreads();

    // owned node (clamped for tail block)
    const int own_s = base + w * 16 + l15;
    const int own   = own_s < N ? own_s : N - 1;

    int xcur = nbr[(size_t)own * 16];

    const float4_t z4 = {0.f, 0.f, 0.f, 0.f};
    float4_t c[8];
#pragma unroll
    for (int dc = 0; dc < 8; ++dc) c[dc] = z4;
    const short8 zs8 = {0, 0, 0, 0, 0, 0, 0, 0};
    short8 hfA[4];
#pragma unroll
    for (int kb = 0; kb < 4; ++kb) hfA[kb] = zs8;

    for (int t = 0; t < 16; ++t) {
        int xn = 0;
        if (t < 15) xn = nbr[(size_t)own * 16 + t + 1];
        const u16* bp = Xih + (size_t)xcur * 512 + 4 * quad;

        u32x2 gb[2][4];   // [parity][gate] gather pipeline, 1 dc ahead
#pragma unroll
        for (int g = 0; g < 4; ++g) gb[0][g] = *(const u32x2*)(bp + 128 * g);

        short8 hfB[4];
#pragma unroll
        for (int dc = 0; dc < 8; ++dc) {
            const int par = dc & 1;
            if (dc < 7) {
#pragma unroll
                for (int g = 0; g < 4; ++g)
                    gb[par ^ 1][g] = *(const u32x2*)(bp + 128 * g + 16 * (dc + 1));
            }
            // z init from gathered Xih (accumulator layout: dims 16dc+4q+r)
            float4_t z[4];
#pragma unroll
            for (int g = 0; g < 4; ++g) {
                u32 w0 = gb[par][g][0], w1 = gb[par][g][1];
                z[g][0] = bitsf(w0 << 16); z[g][1] = bitsf(w0 & 0xFFFF0000u);
                z[g][2] = bitsf(w1 << 16); z[g][3] = bitsf(w1 & 0xFFFF0000u);
            }
            // recurrent GEMM: A-frags from swizzled LDS, B = register h-frags
#pragma unroll
            for (int kb = 0; kb < 4; ++kb)
#pragma unroll
                for (int g = 0; g < 4; ++g) {
                    const short8 whf = *(const short8*)&whs[
                        (128 * g + 16 * dc + l15) * 128 +
                        ((((kb << 2) | quad) ^ l15) << 3)];
                    z[g] = mfma16(whf, hfA[kb], z[g]);
                }
            // gates (pre-scaled domain), cell update, h pack
            float4_t hv;
#pragma unroll
            for (int r = 0; r < 4; ++r) {
                float i_ = __builtin_amdgcn_rcpf(1.f + __builtin_amdgcn_exp2f(z[0][r]));
                float f_ = __builtin_amdgcn_rcpf(1.f + __builtin_amdgcn_exp2f(z[1][r]));
                float g_ = 1.f - 2.f * __builtin_amdgcn_rcpf(1.f + __builtin_amdgcn_exp2f(z[2][r]));
                float o_ = __builtin_amdgcn_rcpf(1.f + __builtin_amdgcn_exp2f(z[3][r]));
                float cc = f_ * c[dc][r] + i_ * g_;
                c[dc][r] = cc;
                hv[r] = o_ * tanh_(cc);
            }
            u32x2 pr;
            pr[0] = pk2bf(hv[1], hv[0]);
            pr[1] = pk2bf(hv[3], hv[2]);
            if (t < 15) {
                // wave-private scr row l15: after pair m, row = dims 32m..+31
                *(u32x2*)&scr[w][l15][8 * par + 2 * quad] = pr;
            } else if (own_s < N) {
                *(u32x2*)(Hout + (size_t)own_s * 128 + 16 * dc + 4 * quad) = pr;
            }
            // after each dc pair, read back the completed kb-frag (in-order DS)
            if (par && t < 15) {
                hfB[dc >> 1] = *(const short8*)&scr[w][l15][4 * quad];
            }
            // fence: no cross-iteration load hoisting (liveness control)
            __builtin_amdgcn_sched_barrier(0);
        }
        if (t < 15) {
#pragma unroll
            for (int kb = 0; kb < 4; ++kb) hfA[kb] = hfB[kb];
            xcur = xn;
        }
    }
}

// ---------------------------------------------------------------------------
__global__ void bn_prep(float* stats, const float* __restrict__ gamma,
                        const float* __restrict__ beta, float invN)
{
    int cidx = threadIdx.x;   // 0..127
    float s = stats[cidx], sq = stats[128 + cidx];
    float mu = s * invN;
    float var = sq * invN - mu * mu;
    float sc = gamma[cidx] * rsqrtf(var + 1e-5f);
    stats[256 + cidx] = sc;
    stats[384 + cidx] = beta[cidx] - mu * sc;
}

template<typename OT>
__global__ __launch_bounds__(256) void bn_apply(
    const float* __restrict__ X, const float* __restrict__ stats,
    OT* __restrict__ Y, int M, int relu)
{
    int gid = blockIdx.x * 256 + threadIdx.x;
    int row = gid >> 4;
    int cs  = (gid & 15) * 8;
    if (row >= M) return;
    float4_t a = *(const float4_t*)(X + (size_t)row * 128 + cs);
    float4_t b = *(const float4_t*)(X + (size_t)row * 128 + cs + 4);
    float v[8];
#pragma unroll
    for (int j = 0; j < 8; ++j) {
        float x = (j < 4) ? a[j] : b[j - 4];
        float t = x * stats[256 + cs + j] + stats[384 + cs + j];
        v[j] = relu ? fmaxf(t, 0.f) : t;
    }
    if constexpr (sizeof(OT) == 2) {
        short8 ov;
#pragma unroll
        for (int j = 0; j < 8; ++j) ov[j] = (short)f2bf(v[j]);
        *(short8*)((u16*)Y + (size_t)row * 128 + cs) = ov;
    } else {
        float4_t o1, o2;
#pragma unroll
        for (int j = 0; j < 4; ++j) { o1[j] = v[j]; o2[j] = v[4 + j]; }
        *(float4_t*)((float*)Y + (size_t)row * 128 + cs) = o1;
        *(float4_t*)((float*)Y + (size_t)row * 128 + cs + 4) = o2;
    }
}

// ---------------------------------------------------------------------------
extern "C" void kernel_launch(void* const* d_in, const int* in_sizes, int n_in,
                              void* d_out, int out_size, void* d_ws, size_t ws_size,
                              hipStream_t stream)
{
    const float* in_feat = (const float*)d_in[0];
    const int*   nbr     = (const int*)d_in[1];
    const float* Wih1 = (const float*)d_in[2];
    const float* Whh1 = (const float*)d_in[3];
    const float* bih1 = (const float*)d_in[4];
    const float* bhh1 = (const float*)d_in[5];
    const float* Wself1  = (const float*)d_in[6];
    const float* bself1  = (const float*)d_in[7];
    const float* Wneigh1 = (const float*)d_in[8];
    const float* gamma1  = (const float*)d_in[9];
    const float* beta1   = (const float*)d_in[10];
    const float* Wih2 = (const float*)d_in[11];
    const float* Whh2 = (const float*)d_in[12];
    const float* bih2 = (const float*)d_in[13];
    const float* bhh2 = (const float*)d_in[14];
    const float* Wself2  = (const float*)d_in[15];
    const float* bself2  = (const float*)d_in[16];
    const float* Wneigh2 = (const float*)d_in[17];
    const float* gamma2  = (const float*)d_in[18];
    const float* beta2   = (const float*)d_in[19];

    const int N = in_sizes[0] / 128;

    char* ws = (char*)d_ws;
    u16*   Xih   = (u16*)ws;                       // [N,512] bf16 (aliases Pbuf)
    float* Pbuf  = (float*)ws;                     // [N,128] f32
    u16*   hn    = (u16*)(ws + (size_t)N * 1024);  // [N,128] bf16
    float* stats = (float*)(ws + (size_t)N * 1024 + (size_t)N * 256);
    u16*   hcur  = (u16*)d_out;                    // bf16 scratch inside d_out

    const int nblk = (N + 63) / 64;
    const int lblk = (N + 127) / 128;
    const float invN = 1.0f / (float)N;
    const int bnblk = (N * 16 + 255) / 256;

    // ---------------- layer 1 ----------------
    gemm_ih<float><<<dim3(nblk, 4), dim3(256), 0, stream>>>(in_feat, Wih1, bih1, bhh1, Xih, stats, N);
    lstm_kernel<<<dim3(lblk), dim3(512), 0, stream>>>(Xih, nbr, Whh1, hn, N);
    gemm_out<float><<<dim3(nblk, 1), dim3(256), 0, stream>>>(hn, Wneigh1, in_feat, Wself1,
                                                             bself1, Pbuf, stats, N);
    bn_prep<<<dim3(1), dim3(128), 0, stream>>>(stats, gamma1, beta1, invN);
    bn_apply<u16><<<dim3(bnblk), dim3(256), 0, stream>>>(Pbuf, stats, hcur, N, 1);

    // ---------------- layer 2 ----------------
    gemm_ih<u16><<<dim3(nblk, 4), dim3(256), 0, stream>>>(hcur, Wih2, bih2, bhh2, Xih, stats, N);
    lstm_kernel<<<dim3(lblk), dim3(512), 0, stream>>>(Xih, nbr, Whh2, hn, N);
    gemm_out<u16><<<dim3(nblk, 1), dim3(256), 0, stream>>>(hn, Wneigh2, hcur, Wself2,
                                                           bself2, Pbuf, stats, N);
    bn_prep<<<dim3(1), dim3(128), 0, stream>>>(stats, gamma2, beta2, invN);
    bn_apply<float><<<dim3(bnblk), dim3(256), 0, stream>>>(Pbuf, stats, (float*)d_out, N, 0);
}